// Round 1
// baseline (293.664 us; speedup 1.0000x reference)
//
#include <hip/hip_runtime.h>
#include <hip/hip_bf16.h>
#include <cstddef>

#define D_DIM 768
#define V_DIM 10240
#define ROWS  32768          // B*N = 8*4096
#define BM    64             // rows per block (full N=768 per block)
#define BK    32
#define KTILES (D_DIM / BK)  // 24

using bf16x8 = __attribute__((ext_vector_type(8))) __bf16;
using bf16x4 = __attribute__((ext_vector_type(4))) __bf16;
using f32x4  = __attribute__((ext_vector_type(4))) float;

// ---------------------------------------------------------------------------
// Pre-pass: fold permutation + 2*(x-0.5) affine into weights.
// W'[d][j] = 2 * W[d][perm(j)],  perm(j) = (j%3)*256 + (j/48)*16 + (j/3)%16
// bias[d]  = -sum_k W[d][k]
// LDS-staged so both the read and the permuted write are coalesced.
// ---------------------------------------------------------------------------
__global__ void prep_w(const float* __restrict__ W, __bf16* __restrict__ Wp,
                       float* __restrict__ bias) {
    __shared__ float row[D_DIM];
    __shared__ float red[256];
    const int d = blockIdx.x;
    const int t = threadIdx.x;
    float s = 0.f;
    for (int k = t; k < D_DIM; k += 256) {
        float w = W[(size_t)d * D_DIM + k];
        row[k] = w;
        s += w;
    }
    red[t] = s;
    __syncthreads();
    for (int off = 128; off > 0; off >>= 1) {
        if (t < off) red[t] += red[t + off];
        __syncthreads();
    }
    if (t == 0) bias[d] = -red[0];
    for (int j = t; j < D_DIM; j += 256) {
        int c  = j % 3;
        int pw = (j / 3) & 15;
        int ph = j / 48;
        Wp[(size_t)d * D_DIM + j] = (__bf16)(2.0f * row[c * 256 + ph * 16 + pw]);
    }
}

// ---------------------------------------------------------------------------
// Fused GEMM: each block owns BM=64 rows x full N=768 cols.
//  - A (fp32 X) read ONCE from HBM, converted to bf16 in-register, staged in
//    a tiny double-buffered LDS chunk (reg-staged so we can swizzle).
//  - B (Wp, 1.1 MB, L2-resident) staged per K-step via global_load_lds w=16,
//    double-buffered, with XOR-swizzled *source* addressing (linear LDS dest).
//  - One barrier per K-step; next tile's loads issued before current MFMAs.
//  - Epilogue fuses bias + pos-table add + aux outputs (rows are exclusive).
// Swizzle: 16B-unit index u' = u ^ ((row>>1)&3) on a 64B row stride, so the
// 8 consecutive lanes of a ds_read_b128 phase hit 8 distinct 4-bank groups.
// ---------------------------------------------------------------------------
__launch_bounds__(512, 2)
__global__ void gemm_fused(const float* __restrict__ X, const __bf16* __restrict__ Wp,
                           const float* __restrict__ bias, const float* __restrict__ ptab,
                           const int* __restrict__ coord, const int* __restrict__ valid,
                           float* __restrict__ out0, float* __restrict__ out1,
                           float* __restrict__ out2) {
    __shared__ __align__(16) __bf16 la[2][BM * BK];     // 2 x 4 KB
    __shared__ __align__(16) __bf16 lb[2][D_DIM * BK];  // 2 x 48 KB

    const int tid  = threadIdx.x;
    const int lane = tid & 63;
    const int wave = tid >> 6;
    const int wr   = (wave >> 2) * 32;   // wave row offset   (2 row groups)
    const int wc   = (wave & 3) * 192;   // wave col offset   (4 col groups)
    const int lr   = lane & 15;
    const int qh   = lane >> 4;          // k-quarter / 16B unit index

    const int m0 = blockIdx.x * BM;

    // Aux outputs: rows m0..m0+63 are owned exclusively by this block.
    if (tid < BM) {
        int m  = m0 + tid;
        int c0 = coord[2 * m];
        int c1 = coord[2 * m + 1];
        out1[2 * m]     = (float)c1;
        out1[2 * m + 1] = (float)c0;
        out2[m] = valid[m] ? 0.0f : 1.0f;
    }

    // ---- B staging descriptors: 6 x global_load_lds(16B) per thread ----
    // unit q in [0,3072): row = q>>2 (0..767), u = q&3 within the 64B row.
    const __bf16* bsrc[6];
    int bdst[6];
    #pragma unroll
    for (int i = 0; i < 6; ++i) {
        int q   = i * 512 + tid;
        int row = q >> 2;
        int su  = (q & 3) ^ ((row >> 1) & 3);       // inverse-swizzled source
        bsrc[i] = Wp + (size_t)row * D_DIM + su * 8;
        bdst[i] = q * 8;                            // linear LDS dest (bf16 elems)
    }

    // ---- A staging descriptors: 1 float4 -> bf16x4 ds_write per thread ----
    const int a_row = tid >> 3;                       // 0..63
    const int a_u   = (tid & 7) >> 1;                 // 16B unit in row
    const int a_h   = tid & 1;                        // 8B half of unit
    const int a_off = a_row * BK + (a_u ^ ((a_row >> 1) & 3)) * 8 + a_h * 4;
    const float* aptr = X + (size_t)(m0 + a_row) * D_DIM + ((tid & 7) << 2);

    // ---- fragment read offsets (swizzled) ----
    int aoff[2], boff[12];
    #pragma unroll
    for (int i = 0; i < 2; ++i) {
        int row = wr + i * 16 + lr;
        aoff[i] = row * BK + (qh ^ ((row >> 1) & 3)) * 8;
    }
    #pragma unroll
    for (int j = 0; j < 12; ++j) {
        int row = wc + j * 16 + lr;
        boff[j] = row * BK + (qh ^ ((row >> 1) & 3)) * 8;
    }

    f32x4 acc[2][12] = {};

    // ---- prologue: stage k-tile 0 into buffer 0 ----
    #pragma unroll
    for (int i = 0; i < 6; ++i)
        __builtin_amdgcn_global_load_lds(
            (const __attribute__((address_space(1))) void*)bsrc[i],
            (__attribute__((address_space(3))) void*)&lb[0][bdst[i]], 16, 0, 0);
    {
        float4 f = *(const float4*)aptr;
        bf16x4 v;
        v[0] = (__bf16)f.x; v[1] = (__bf16)f.y; v[2] = (__bf16)f.z; v[3] = (__bf16)f.w;
        *(bf16x4*)&la[0][a_off] = v;
    }
    __syncthreads();

    // ---- K loop: 1 barrier / iter, stage t+1 issued before compute of t ----
    for (int kt = 0; kt < KTILES; ++kt) {
        const int cur = kt & 1;
        const int nxt = cur ^ 1;
        const int k1  = (kt + 1) * BK;

        float4 fA;
        if (kt + 1 < KTILES) {
            #pragma unroll
            for (int i = 0; i < 6; ++i)
                __builtin_amdgcn_global_load_lds(
                    (const __attribute__((address_space(1))) void*)(bsrc[i] + k1),
                    (__attribute__((address_space(3))) void*)&lb[nxt][bdst[i]], 16, 0, 0);
            fA = *(const float4*)(aptr + k1);
        }

        bf16x8 af0 = *(const bf16x8*)&la[cur][aoff[0]];
        bf16x8 af1 = *(const bf16x8*)&la[cur][aoff[1]];

        #pragma unroll
        for (int j = 0; j < 12; ++j) {
            bf16x8 bfv = *(const bf16x8*)&lb[cur][boff[j]];
            acc[0][j] = __builtin_amdgcn_mfma_f32_16x16x32_bf16(af0, bfv, acc[0][j], 0, 0, 0);
            acc[1][j] = __builtin_amdgcn_mfma_f32_16x16x32_bf16(af1, bfv, acc[1][j], 0, 0, 0);
        }

        if (kt + 1 < KTILES) {
            bf16x4 v;
            v[0] = (__bf16)fA.x; v[1] = (__bf16)fA.y; v[2] = (__bf16)fA.z; v[3] = (__bf16)fA.w;
            *(bf16x4*)&la[nxt][a_off] = v;
        }
        __syncthreads();   // drains vmcnt+lgkmcnt: buffers for t+1 ready
    }

    // ---- epilogue: bias + pos add + store ----
    const float* pt0 = ptab;
    const float* pt1 = ptab + (size_t)V_DIM * D_DIM;

    float bv[12];
    #pragma unroll
    for (int j = 0; j < 12; ++j)
        bv[j] = bias[wc + j * 16 + lr];

    #pragma unroll
    for (int i = 0; i < 2; ++i) {
        #pragma unroll
        for (int r = 0; r < 4; ++r) {
            const int m = m0 + wr + i * 16 + qh * 4 + r;
            int c0 = coord[2 * m];
            int c1 = coord[2 * m + 1];
            if (c0 < 0) c0 = 0;
            if (c1 < 0) c1 = 0;
            const int vld = valid[m];
            const float* p0 = pt0 + (size_t)c1 * D_DIM;
            const float* p1 = pt1 + (size_t)c0 * D_DIM;
            float* orow = out0 + (size_t)m * D_DIM;
            #pragma unroll
            for (int j = 0; j < 12; ++j) {
                const int d = wc + j * 16 + lr;
                float v = acc[i][j][r] + bv[j];
                if (vld)
                    v += p0[d] + p1[d];
                orow[d] = v;
            }
        }
    }
}

extern "C" void kernel_launch(void* const* d_in, const int* in_sizes, int n_in,
                              void* d_out, int out_size, void* d_ws, size_t ws_size,
                              hipStream_t stream) {
    const float* x     = (const float*)d_in[0];
    const int*   coord = (const int*)d_in[1];
    const int*   valid = (const int*)d_in[2];
    const float* W     = (const float*)d_in[3];
    const float* ptab  = (const float*)d_in[4];

    float* out0 = (float*)d_out;                  // [32768][768]
    float* out1 = out0 + (size_t)ROWS * D_DIM;    // [32768][2]
    float* out2 = out1 + (size_t)ROWS * 2;        // [32768]

    // Workspace: [Wp bf16 1.125 MB][bias 3 KB]
    __bf16* Wp   = (__bf16*)d_ws;
    float*  bias = (float*)((char*)d_ws + (size_t)D_DIM * D_DIM * sizeof(__bf16));

    hipLaunchKernelGGL(prep_w, dim3(D_DIM), dim3(256), 0, stream, W, Wp, bias);
    hipLaunchKernelGGL(gemm_fused, dim3(ROWS / BM), dim3(512), 0, stream,
                       x, Wp, bias, ptab, coord, valid, out0, out1, out2);
}